// Round 1
// baseline (1890.117 us; speedup 1.0000x reference)
//
#include <hip/hip_runtime.h>
#include <stdint.h>

typedef unsigned short u16;
typedef unsigned int   u32;
typedef unsigned long long u64;
typedef __bf16 bf16x8 __attribute__((ext_vector_type(8)));
typedef float  f32x4  __attribute__((ext_vector_type(4)));

#define LN_EPS 1e-5f
#define LSEQ   256
#define DM     128
#define B3     768
#define MTOT   196608
#define NQKV   384
#define FFD    2048

__device__ __forceinline__ u16 f2bf(float f) {
  u32 u = __builtin_bit_cast(u32, f);
  u += 0x7FFFu + ((u >> 16) & 1u);
  return (u16)(u >> 16);
}
__device__ __forceinline__ float bf2f(u16 h) {
  u32 u = ((u32)h) << 16;
  return __builtin_bit_cast(float, u);
}
__device__ __forceinline__ bf16x8 ld_bf8(const u16* p) {
  return __builtin_bit_cast(bf16x8, *(const uint4*)p);
}
__device__ __forceinline__ f32x4 mfma16(bf16x8 a, bf16x8 b, f32x4 c) {
  return __builtin_amdgcn_mfma_f32_16x16x32_bf16(a, b, c, 0, 0, 0);
}
// async global->LDS, 16B per lane; lds dest must be wave-uniform-base + lane*16
__device__ __forceinline__ void gload16(const u16* g, u16* l) {
  __builtin_amdgcn_global_load_lds(
      (__attribute__((address_space(1))) void*)(uintptr_t)g,
      (__attribute__((address_space(3))) void*)(uintptr_t)l, 16, 0, 0);
}
__device__ __forceinline__ u64 pack4bf(float a, float b, float c, float d) {
  return (u64)f2bf(a) | ((u64)f2bf(b) << 16) | ((u64)f2bf(c) << 32) | ((u64)f2bf(d) << 48);
}

// ---------------- f32 -> bf16 weight conversion ----------------
__global__ __launch_bounds__(256) void k_cvt(const float* src, u16* dst, int n8) {
  int gid = blockIdx.x * 256 + threadIdx.x;
  if (gid >= n8) return;
  const float* s = src + gid * 8;
  union { u16 o[8]; uint4 v; } t;
#pragma unroll
  for (int j = 0; j < 8; ++j) t.o[j] = f2bf(s[j]);
  *(uint4*)(dst + (size_t)gid * 8) = t.v;
}

// ---------------- embed: zb[row][d] = x*w0[d] + b0[d] (bf16) ----------------
__global__ __launch_bounds__(256) void k_embed(const float* x, const float* xp, const float* xn,
                                               const float* w0, const float* b0, u16* zb) {
  int gid = blockIdx.x * 256 + threadIdx.x; // M*16
  int row = gid >> 4;
  int oct = gid & 15;
  int br  = row >> 16;
  int loc = row & 65535;
  const float* xs = br == 0 ? x : (br == 1 ? xp : xn);
  float xv = xs[loc];
  int d0 = oct * 8;
  union { u16 o[8]; uint4 v; } t;
#pragma unroll
  for (int j = 0; j < 8; ++j) t.o[j] = f2bf(xv * w0[d0 + j] + b0[d0 + j]);
  *(uint4*)(zb + (size_t)row * DM + d0) = t.v;
}

// ---------------- QKV GEMM: out[m][n] = zb[m]·Wqkv[n] + bias (bf16 out) -----
// A-op = weight rows (n), B-op = zb rows (m): D frag row=n(4g+r), col=m(l&15)
__global__ __launch_bounds__(256) void k_qkv(const u16* zb, const u16* wt, const float* bias, u16* out) {
  __shared__ union {
    struct { u16 A[16384]; u16 B[16384]; } s;
    u16 bounce[128 * 136];
  } u;
  int tid = threadIdx.x;
  int m0 = blockIdx.x * 128;
  int n0 = blockIdx.y * 128;
#pragma unroll
  for (int p = 0; p < 8; ++p) {
    int row = p * 16 + (tid >> 4);
    int gs = (tid & 15) ^ (row & 7);
    gload16(wt + (u64)(n0 + row) * 128 + gs * 8, u.s.A + p * 2048 + tid * 8);
  }
#pragma unroll
  for (int p = 0; p < 8; ++p) {
    int row = p * 16 + (tid >> 4);
    int gs = (tid & 15) ^ (row & 7);
    gload16(zb + (u64)(m0 + row) * 128 + gs * 8, u.s.B + p * 2048 + tid * 8);
  }
  __syncthreads();

  int lane = tid & 63, wv = tid >> 6;
  int l15 = lane & 15, g = lane >> 4;
  int wn = wv & 1, wm = wv >> 1;
  f32x4 acc[4][4] = {};
#pragma unroll
  for (int ks = 0; ks < 4; ++ks) {
    bf16x8 a[4], b[4];
#pragma unroll
    for (int i = 0; i < 4; ++i) {
      int row = wn * 64 + i * 16 + l15;
      int gz = (ks * 4 + g) ^ (row & 7);
      a[i] = ld_bf8(u.s.A + row * 128 + gz * 8);
    }
#pragma unroll
    for (int j = 0; j < 4; ++j) {
      int row = wm * 64 + j * 16 + l15;
      int gz = (ks * 4 + g) ^ (row & 7);
      b[j] = ld_bf8(u.s.B + row * 128 + gz * 8);
    }
#pragma unroll
    for (int i = 0; i < 4; ++i)
#pragma unroll
      for (int j = 0; j < 4; ++j) acc[i][j] = mfma16(a[i], b[j], acc[i][j]);
  }
  float bv[4][4];
#pragma unroll
  for (int i = 0; i < 4; ++i)
    *(f32x4*)bv[i] = *(const f32x4*)(bias + n0 + wn * 64 + i * 16 + g * 4);
  __syncthreads(); // A/B dead -> bounce
#pragma unroll
  for (int i = 0; i < 4; ++i) {
    int nq = wn * 64 + i * 16 + g * 4;
#pragma unroll
    for (int j = 0; j < 4; ++j) {
      int m = wm * 64 + j * 16 + l15;
      u64 pk = pack4bf(acc[i][j][0] + bv[i][0], acc[i][j][1] + bv[i][1],
                       acc[i][j][2] + bv[i][2], acc[i][j][3] + bv[i][3]);
      *(u64*)(u.bounce + m * 136 + nq) = pk;
    }
  }
  __syncthreads();
  {
    int row = tid >> 1, half = tid & 1;
    const u16* src = u.bounce + row * 136 + half * 64;
    u16* dst = out + (u64)(m0 + row) * NQKV + n0 + half * 64;
#pragma unroll
    for (int q = 0; q < 8; ++q) *(uint4*)(dst + q * 8) = *(const uint4*)(src + q * 8);
  }
}

// ---------------- attention: per (seq,head) block ----------------
// S^T = K·Q^T (A-op=K rows, B-op=Q rows) -> plain exp (scores tiny) ->
// P packed b64 to LDS -> O^T = VT·P^T (A-op=VT rows, B-op=P rows)
__global__ __launch_bounds__(256) void k_attn(const u16* qkv, const unsigned char* mk0,
                                              const unsigned char* mk1, const unsigned char* mk2,
                                              u16* attno) {
  __shared__ u16 VT[32 * 264];
  __shared__ u16 P[4][64 * 72];
  __shared__ float pen[256];
  int tid = threadIdx.x;
  int bh = blockIdx.x;
  int bb = bh >> 2, h = bh & 3;
  {
    int br = bb >> 8, loc = bb & 255;
    const unsigned char* mp = br == 0 ? mk0 : (br == 1 ? mk1 : mk2);
    pen[tid] = mp[loc * 256 + tid] ? -1e9f : 0.0f;
  }
  {
    const u16* vsrc = qkv + (u64)(bb * 256 + tid) * NQKV + 256 + h * 32;
    u16 tmp[32];
    *(uint4*)(tmp) = *(const uint4*)vsrc;
    *(uint4*)(tmp + 8) = *(const uint4*)(vsrc + 8);
    *(uint4*)(tmp + 16) = *(const uint4*)(vsrc + 16);
    *(uint4*)(tmp + 24) = *(const uint4*)(vsrc + 24);
#pragma unroll
    for (int d = 0; d < 32; ++d) VT[d * 264 + tid] = tmp[d];
  }
  __syncthreads();

  int lane = tid & 63, wv = tid >> 6;
  int l15 = lane & 15, g = lane >> 4;
  const float scale = 0.17677669529663687f;

  bf16x8 qf[4];
#pragma unroll
  for (int j = 0; j < 4; ++j)
    qf[j] = ld_bf8(qkv + (u64)(bb * 256 + wv * 64 + j * 16 + l15) * NQKV + h * 32 + g * 8);
  bf16x8 kf[16];
#pragma unroll
  for (int kb = 0; kb < 16; ++kb)
    kf[kb] = ld_bf8(qkv + (u64)(bb * 256 + kb * 16 + l15) * NQKV + 128 + h * 32 + g * 8);

  f32x4 accO[2][4] = {};
  float lpart[4] = {0.f, 0.f, 0.f, 0.f};
  u16* Pw = &P[wv][0];
  f32x4 zf = {0.f, 0.f, 0.f, 0.f};

#pragma unroll
  for (int t = 0; t < 4; ++t) {
    f32x4 pq[4];
#pragma unroll
    for (int i = 0; i < 4; ++i) pq[i] = *(const f32x4*)(pen + t * 64 + i * 16 + g * 4);
#pragma unroll
    for (int jq = 0; jq < 4; ++jq) {
      f32x4 s[4];
#pragma unroll
      for (int i = 0; i < 4; ++i) s[i] = mfma16(kf[t * 4 + i], qf[jq], zf);
#pragma unroll
      for (int i = 0; i < 4; ++i) {
        float p0 = __expf(fmaf(s[i][0], scale, pq[i][0]));
        float p1 = __expf(fmaf(s[i][1], scale, pq[i][1]));
        float p2 = __expf(fmaf(s[i][2], scale, pq[i][2]));
        float p3 = __expf(fmaf(s[i][3], scale, pq[i][3]));
        lpart[jq] += (p0 + p1) + (p2 + p3);
        *(u64*)(Pw + (jq * 16 + l15) * 72 + i * 16 + g * 4) = pack4bf(p0, p1, p2, p3);
      }
    }
    __syncthreads(); // P visible (also pins LDS op order across type-punned views)
#pragma unroll
    for (int ks = 0; ks < 2; ++ks) {
      bf16x8 va[2], pb[4];
#pragma unroll
      for (int i = 0; i < 2; ++i)
        va[i] = ld_bf8(VT + (i * 16 + l15) * 264 + t * 64 + ks * 32 + g * 8);
#pragma unroll
      for (int jq = 0; jq < 4; ++jq)
        pb[jq] = ld_bf8(Pw + (jq * 16 + l15) * 72 + ks * 32 + g * 8);
#pragma unroll
      for (int i = 0; i < 2; ++i)
#pragma unroll
        for (int jq = 0; jq < 4; ++jq) accO[i][jq] = mfma16(va[i], pb[jq], accO[i][jq]);
    }
    __syncthreads(); // P consumed before next tile overwrites
  }
#pragma unroll
  for (int jq = 0; jq < 4; ++jq) {
    float v = lpart[jq];
    v += __shfl_xor(v, 16);
    v += __shfl_xor(v, 32);
    lpart[jq] = 1.0f / v;
  }
#pragma unroll
  for (int i = 0; i < 2; ++i)
#pragma unroll
    for (int jq = 0; jq < 4; ++jq) {
      int q = wv * 64 + jq * 16 + l15;
      float li = lpart[jq];
      u64 pk = pack4bf(accO[i][jq][0] * li, accO[i][jq][1] * li,
                       accO[i][jq][2] * li, accO[i][jq][3] * li);
      *(u64*)(attno + ((u64)(bb * 4 + h) * 256 + q) * 32 + i * 16 + g * 4) = pk;
    }
}

// ---------------- O-proj + bias + residual + LN1 (in-place zb) ----------------
__global__ __launch_bounds__(256) void k_oln(const u16* attno, const u16* wt, const float* bias,
                                             const float* lns, const float* lnb, u16* zb) {
  __shared__ union {
    struct { u16 A[16384]; u16 B[16384]; } s;
    float bounce[64 * 132];
  } u;
  int tid = threadIdx.x;
  int m0 = blockIdx.x * 128;
#pragma unroll
  for (int p = 0; p < 8; ++p) {
    int row = p * 16 + (tid >> 4);
    int gs = (tid & 15) ^ (row & 7);
    gload16(wt + (u64)row * 128 + gs * 8, u.s.A + p * 2048 + tid * 8);
  }
  int bb = m0 >> 8, lbase = m0 & 255;
#pragma unroll
  for (int p = 0; p < 8; ++p) {
    int row = p * 16 + (tid >> 4);
    int gs = (tid & 15) ^ (row & 7);
    int hh = gs >> 2, off = (gs & 3) * 8;
    gload16(attno + ((u64)(bb * 4 + hh) * 256 + lbase + row) * 32 + off,
            u.s.B + p * 2048 + tid * 8);
  }
  __syncthreads();

  int lane = tid & 63, wv = tid >> 6;
  int l15 = lane & 15, g = lane >> 4;
  int wn = wv & 1, wm = wv >> 1;
  f32x4 acc[4][4] = {};
#pragma unroll
  for (int ks = 0; ks < 4; ++ks) {
    bf16x8 a[4], b[4];
#pragma unroll
    for (int i = 0; i < 4; ++i) {
      int row = wn * 64 + i * 16 + l15;
      int gz = (ks * 4 + g) ^ (row & 7);
      a[i] = ld_bf8(u.s.A + row * 128 + gz * 8);
    }
#pragma unroll
    for (int j = 0; j < 4; ++j) {
      int row = wm * 64 + j * 16 + l15;
      int gz = (ks * 4 + g) ^ (row & 7);
      b[j] = ld_bf8(u.s.B + row * 128 + gz * 8);
    }
#pragma unroll
    for (int i = 0; i < 4; ++i)
#pragma unroll
      for (int j = 0; j < 4; ++j) acc[i][j] = mfma16(a[i], b[j], acc[i][j]);
  }
  for (int ph = 0; ph < 2; ++ph) {
    __syncthreads();
    if (wm == ph) {
#pragma unroll
      for (int i = 0; i < 4; ++i)
#pragma unroll
        for (int j = 0; j < 4; ++j) {
          int ml = j * 16 + l15;
          int nq = wn * 64 + i * 16 + g * 4;
          *(f32x4*)(u.bounce + ml * 132 + nq) = acc[i][j];
        }
    }
    __syncthreads();
    {
      int ql = tid >> 2, q4 = tid & 3;
      int mrow = m0 + ph * 64 + ql;
      const u16* zrow = zb + (u64)mrow * 128 + q4 * 32;
      float v[32];
      float s = 0.f, s2 = 0.f;
#pragma unroll
      for (int c = 0; c < 32; ++c) {
        float val = u.bounce[ql * 132 + q4 * 32 + c] + bias[q4 * 32 + c] + bf2f(zrow[c]);
        v[c] = val; s += val; s2 += val * val;
      }
      s += __shfl_xor(s, 1);  s += __shfl_xor(s, 2);
      s2 += __shfl_xor(s2, 1); s2 += __shfl_xor(s2, 2);
      float mean = s * (1.0f / 128.0f);
      float var = s2 * (1.0f / 128.0f) - mean * mean;
      float rstd = rsqrtf(var + LN_EPS);
      union { u16 o[32]; uint4 q[4]; } t;
#pragma unroll
      for (int c = 0; c < 32; ++c)
        t.o[c] = f2bf((v[c] - mean) * rstd * lns[q4 * 32 + c] + lnb[q4 * 32 + c]);
      u16* dst = zb + (u64)mrow * 128 + q4 * 32;
#pragma unroll
      for (int q = 0; q < 4; ++q) *(uint4*)(dst + q * 8) = t.q[q];
    }
  }
}

// ---------------- fused FF: relu(zb·W1^T+b1)·W2^T + b2 + residual + LN2 ------
__global__ __launch_bounds__(256) void k_ffn(u16* zb, const u16* w1, const float* b1,
                                             const u16* w2, const float* b2,
                                             const float* lns, const float* lnb) {
  __shared__ union {
    struct { u16 W1[8192]; u16 W2[8192]; u16 H1[8192]; } s;
    float bounce[64 * 132];
  } u;
  int tid = threadIdx.x;
  int m0 = blockIdx.x * 128;
  int lane = tid & 63, wv = tid >> 6;
  int l15 = lane & 15, g = lane >> 4;
  int qh1 = (wv & 1) * 64;                 // gemm1 q-half
  int ffh = (wv >> 1) * 32;                // gemm1 ff-half
  int dh = (wv & 1) * 64, qh2 = (wv >> 1) * 64; // gemm2 split

  bf16x8 az[4][4]; // zb B-op frags, reused for all 32 chunks
#pragma unroll
  for (int j = 0; j < 4; ++j)
#pragma unroll
    for (int ks = 0; ks < 4; ++ks)
      az[j][ks] = ld_bf8(zb + (u64)(m0 + qh1 + j * 16 + l15) * 128 + ks * 32 + g * 8);

  f32x4 acc2[4][4] = {};
  for (int c = 0; c < 32; ++c) {
#pragma unroll
    for (int p = 0; p < 4; ++p) {
      int row = p * 16 + (tid >> 4);
      int gs = (tid & 15) ^ (row & 7);
      gload16(w1 + (u64)(c * 64 + row) * 128 + gs * 8, u.s.W1 + p * 2048 + tid * 8);
    }
#pragma unroll
    for (int p = 0; p < 4; ++p) {
      int row = p * 32 + (tid >> 3);
      int gs = (tid & 7) ^ (row & 7);
      gload16(w2 + (u64)row * FFD + c * 64 + gs * 8, u.s.W2 + p * 2048 + tid * 8);
    }
    __syncthreads(); // W staged; H1(prev) consumed
    {
      f32x4 a1[2][4] = {};
#pragma unroll
      for (int ks = 0; ks < 4; ++ks) {
        bf16x8 af[2];
#pragma unroll
        for (int i = 0; i < 2; ++i) {
          int row = ffh + i * 16 + l15;
          int gz = (ks * 4 + g) ^ (row & 7);
          af[i] = ld_bf8(u.s.W1 + row * 128 + gz * 8);
        }
#pragma unroll
        for (int i = 0; i < 2; ++i)
#pragma unroll
          for (int j = 0; j < 4; ++j) a1[i][j] = mfma16(af[i], az[j][ks], a1[i][j]);
      }
#pragma unroll
      for (int i = 0; i < 2; ++i) {
        float bq[4];
        *(f32x4*)bq = *(const f32x4*)(b1 + c * 64 + ffh + i * 16 + g * 4);
#pragma unroll
        for (int j = 0; j < 4; ++j) {
          int q = qh1 + j * 16 + l15;
          int f0 = ffh + i * 16 + g * 4;
          float t0 = a1[i][j][0] + bq[0]; t0 = t0 > 0.f ? t0 : 0.f;
          float t1 = a1[i][j][1] + bq[1]; t1 = t1 > 0.f ? t1 : 0.f;
          float t2 = a1[i][j][2] + bq[2]; t2 = t2 > 0.f ? t2 : 0.f;
          float t3 = a1[i][j][3] + bq[3]; t3 = t3 > 0.f ? t3 : 0.f;
          int gz = (f0 >> 3) ^ (q & 7);
          *(u64*)(u.s.H1 + q * 64 + gz * 8 + (f0 & 7)) = pack4bf(t0, t1, t2, t3);
        }
      }
    }
    __syncthreads(); // H1 ready
    {
#pragma unroll
      for (int ks = 0; ks < 2; ++ks) {
        bf16x8 af[4], bfr[4];
#pragma unroll
        for (int i = 0; i < 4; ++i) {
          int row = dh + i * 16 + l15;
          int gz = (ks * 4 + g) ^ (row & 7);
          af[i] = ld_bf8(u.s.W2 + row * 64 + gz * 8);
        }
#pragma unroll
        for (int j = 0; j < 4; ++j) {
          int q = qh2 + j * 16 + l15;
          int gz = (ks * 4 + g) ^ (q & 7);
          bfr[j] = ld_bf8(u.s.H1 + q * 64 + gz * 8);
        }
#pragma unroll
        for (int i = 0; i < 4; ++i)
#pragma unroll
          for (int j = 0; j < 4; ++j) acc2[i][j] = mfma16(af[i], bfr[j], acc2[i][j]);
      }
    }
    __syncthreads(); // gemm2 reads done before restage
  }
  // epilogue: bias + residual + LN2, two 64-row phases
  for (int ph = 0; ph < 2; ++ph) {
    __syncthreads();
    if ((wv >> 1) == ph) {
#pragma unroll
      for (int i = 0; i < 4; ++i)
#pragma unroll
        for (int j = 0; j < 4; ++j) {
          int ml = j * 16 + l15;
          int nq = dh + i * 16 + g * 4;
          *(f32x4*)(u.bounce + ml * 132 + nq) = acc2[i][j];
        }
    }
    __syncthreads();
    {
      int ql = tid >> 2, q4 = tid & 3;
      int mrow = m0 + ph * 64 + ql;
      const u16* zrow = zb + (u64)mrow * 128 + q4 * 32;
      float v[32];
      float s = 0.f, s2 = 0.f;
#pragma unroll
      for (int c = 0; c < 32; ++c) {
        float val = u.bounce[ql * 132 + q4 * 32 + c] + b2[q4 * 32 + c] + bf2f(zrow[c]);
        v[c] = val; s += val; s2 += val * val;
      }
      s += __shfl_xor(s, 1);  s += __shfl_xor(s, 2);
      s2 += __shfl_xor(s2, 1); s2 += __shfl_xor(s2, 2);
      float mean = s * (1.0f / 128.0f);
      float var = s2 * (1.0f / 128.0f) - mean * mean;
      float rstd = rsqrtf(var + LN_EPS);
      union { u16 o[32]; uint4 q[4]; } t;
#pragma unroll
      for (int c = 0; c < 32; ++c)
        t.o[c] = f2bf((v[c] - mean) * rstd * lns[q4 * 32 + c] + lnb[q4 * 32 + c]);
      u16* dst = zb + (u64)mrow * 128 + q4 * 32;
#pragma unroll
      for (int q = 0; q < 4; ++q) *(uint4*)(dst + q * 8) = t.q[q];
    }
  }
}

// ---------------- mean over seq ----------------
__global__ __launch_bounds__(256) void k_mean(const u16* zb, float* h) {
  __shared__ float part[4][128];
  int tid = threadIdx.x, bb = blockIdx.x;
  int d2 = tid & 63, lg = tid >> 6;
  float s0 = 0.f, s1 = 0.f;
  for (int li = 0; li < 64; ++li) {
    int l = lg * 64 + li;
    u32 v = *(const u32*)(zb + (u64)(bb * 256 + l) * 128 + d2 * 2);
    s0 += bf2f((u16)(v & 0xffffu));
    s1 += bf2f((u16)(v >> 16));
  }
  part[lg][d2 * 2] = s0;
  part[lg][d2 * 2 + 1] = s1;
  __syncthreads();
  if (tid < 128) {
    float s = part[0][tid] + part[1][tid] + part[2][tid] + part[3][tid];
    h[bb * 128 + tid] = s * (1.0f / 256.0f);
  }
}

// ---------------- head: tanh(tanh(h W1^T + b1) W2^T + b2) ----------------
__global__ __launch_bounds__(128) void k_head(const float* h, const float* w1, const float* b1,
                                              const float* w2, const float* b2, float* h2) {
  __shared__ float r0[128], r1[128];
  int tid = threadIdx.x, bb = blockIdx.x;
  r0[tid] = h[bb * 128 + tid];
  __syncthreads();
  float s = b1[tid];
  const float* wr = w1 + tid * 128;
  for (int k = 0; k < 128; ++k) s += r0[k] * wr[k];
  r1[tid] = tanhf(s);
  __syncthreads();
  float s2 = b2[tid];
  const float* wr2 = w2 + tid * 128;
  for (int k = 0; k < 128; ++k) s2 += r1[k] * wr2[k];
  h2[bb * 128 + tid] = tanhf(s2);
}

// ---------------- finalize: nrm rows, nb/hp/hn outputs, logits ----------------
__global__ __launch_bounds__(128) void k_finalize(const float* h2, const float* w3, const float* b3,
                                                  float* nrm, float* out) {
  __shared__ float row[128];
  __shared__ float red[2];
  __shared__ float lg[3];
  int tid = threadIdx.x, i = blockIdx.x;
  float v = h2[i * 128 + tid];
  row[tid] = v;
  float sq = v * v;
#pragma unroll
  for (int o = 32; o; o >>= 1) sq += __shfl_xor(sq, o);
  if ((tid & 63) == 0) red[tid >> 6] = sq;
  __syncthreads();
  float rinv = rsqrtf(red[0] + red[1]);
  float nv = v * rinv;
  nrm[i * 128 + tid] = nv;
  int br = i >> 8, loc = i & 255;
  if (br == 0)      out[loc * 128 + tid] = nv;
  else if (br == 1) out[32768 + loc * 128 + tid] = v;
  else              out[65536 + loc * 128 + tid] = v;
  if (br == 0) {
    if (tid < 3) {
      float s = b3[tid];
      const float* wr = w3 + tid * 128;
      for (int k = 0; k < 128; ++k) s += row[k] * wr[k];
      lg[tid] = s;
    }
    __syncthreads();
    if (tid == 0) {
      float m = fmaxf(lg[0], fmaxf(lg[1], lg[2]));
      float e0 = __expf(lg[0] - m), e1 = __expf(lg[1] - m), e2 = __expf(lg[2] - m);
      float si = 1.0f / (e0 + e1 + e2);
      out[98304 + loc * 3 + 0] = e0 * si;
      out[98304 + loc * 3 + 1] = e1 * si;
      out[98304 + loc * 3 + 2] = e2 * si;
    }
  }
}

// ---------------- InfoNCE per-row partial ----------------
__global__ __launch_bounds__(256) void k_infonce(const float* nrm, float* partial) {
  __shared__ float nbi[128];
  __shared__ float red[8];
  __shared__ float posv;
  int tid = threadIdx.x, i = blockIdx.x;
  if (tid < 128) nbi[tid] = nrm[i * 128 + tid];
  __syncthreads();
  const float* a = nrm + (u64)(256 + tid) * 128;
  const float* b = nrm + (u64)(512 + tid) * 128;
  float s1 = 0.f, s2 = 0.f;
  for (int k = 0; k < 128; ++k) { s1 += nbi[k] * a[k]; s2 += nbi[k] * b[k]; }
  s1 *= 20.0f; s2 *= 20.0f;
  if (tid == i) posv = s1;
  float m = fmaxf(s1, s2);
#pragma unroll
  for (int o = 32; o; o >>= 1) m = fmaxf(m, __shfl_xor(m, o));
  if ((tid & 63) == 0) red[tid >> 6] = m;
  __syncthreads();
  float M = fmaxf(fmaxf(red[0], red[1]), fmaxf(red[2], red[3]));
  float e = __expf(s1 - M) + __expf(s2 - M);
#pragma unroll
  for (int o = 32; o; o >>= 1) e += __shfl_xor(e, o);
  if ((tid & 63) == 0) red[4 + (tid >> 6)] = e;
  __syncthreads();
  if (tid == 0) {
    float S = red[4] + red[5] + red[6] + red[7];
    partial[i] = logf(S) + M - posv;
  }
}

__global__ __launch_bounds__(256) void k_loss(const float* partial, float* out) {
  int tid = threadIdx.x;
  float v = partial[tid];
#pragma unroll
  for (int o = 32; o; o >>= 1) v += __shfl_xor(v, o);
  __shared__ float red[4];
  if ((tid & 63) == 0) red[tid >> 6] = v;
  __syncthreads();
  if (tid == 0) out[99072] = (red[0] + red[1] + red[2] + red[3]) * (1.0f / 256.0f);
}

extern "C" void kernel_launch(void* const* d_in, const int* in_sizes, int n_in,
                              void* d_out, int out_size, void* d_ws, size_t ws_size,
                              hipStream_t stream) {
  const float* x   = (const float*)d_in[0];
  const float* xp  = (const float*)d_in[1];
  const float* xn  = (const float*)d_in[2];
  const unsigned char* mk0 = (const unsigned char*)d_in[3];
  const unsigned char* mk1 = (const unsigned char*)d_in[4];
  const unsigned char* mk2 = (const unsigned char*)d_in[5];
  const float* w0   = (const float*)d_in[6];
  const float* b0   = (const float*)d_in[7];
  const float* wqkv = (const float*)d_in[8];
  const float* bqkv = (const float*)d_in[9];
  const float* wo   = (const float*)d_in[10];
  const float* bo   = (const float*)d_in[11];
  const float* wf1  = (const float*)d_in[12];
  const float* bf1  = (const float*)d_in[13];
  const float* wf2  = (const float*)d_in[14];
  const float* bf2v = (const float*)d_in[15];
  const float* l1s  = (const float*)d_in[16];
  const float* l1b  = (const float*)d_in[17];
  const float* l2s  = (const float*)d_in[18];
  const float* l2b  = (const float*)d_in[19];
  const float* w1   = (const float*)d_in[20];
  const float* b1   = (const float*)d_in[21];
  const float* w2   = (const float*)d_in[22];
  const float* b2   = (const float*)d_in[23];
  const float* w3   = (const float*)d_in[24];
  const float* b3   = (const float*)d_in[25];
  float* out = (float*)d_out;

  // workspace layout (needs ~245 MiB)
  char* ws = (char*)d_ws;
  u16* zb    = (u16*)ws; ws += (size_t)MTOT * 128 * 2;
  u16* qkv   = (u16*)ws; ws += (size_t)MTOT * 384 * 2;
  u16* attno = (u16*)ws; ws += (size_t)MTOT * 128 * 2;
  u16* wqb   = (u16*)ws; ws += (size_t)3 * 384 * 128 * 2;
  u16* wob   = (u16*)ws; ws += (size_t)3 * 128 * 128 * 2;
  u16* wf1b  = (u16*)ws; ws += (size_t)3 * 2048 * 128 * 2;
  u16* wf2b  = (u16*)ws; ws += (size_t)3 * 128 * 2048 * 2;
  float* hbuf = (float*)ws; ws += (size_t)768 * 128 * 4;
  float* h2   = (float*)ws; ws += (size_t)768 * 128 * 4;
  float* nrm  = (float*)ws; ws += (size_t)768 * 128 * 4;
  float* partial = (float*)ws;

  k_cvt<<<72, 256, 0, stream>>>(wqkv, wqb, 3 * 384 * 128 / 8);
  k_cvt<<<24, 256, 0, stream>>>(wo, wob, 3 * 128 * 128 / 8);
  k_cvt<<<384, 256, 0, stream>>>(wf1, wf1b, 3 * 2048 * 128 / 8);
  k_cvt<<<384, 256, 0, stream>>>(wf2, wf2b, 3 * 128 * 2048 / 8);
  k_embed<<<12288, 256, 0, stream>>>(x, xp, xn, w0, b0, zb);

  for (int l = 0; l < 3; ++l) {
    k_qkv<<<dim3(1536, 3), 256, 0, stream>>>(zb, wqb + (size_t)l * 384 * 128,
                                             bqkv + l * 384, qkv);
    k_attn<<<3072, 256, 0, stream>>>(qkv, mk0, mk1, mk2, attno);
    k_oln<<<1536, 256, 0, stream>>>(attno, wob + (size_t)l * 128 * 128, bo + l * 128,
                                    l1s + l * 128, l1b + l * 128, zb);
    k_ffn<<<1536, 256, 0, stream>>>(zb, wf1b + (size_t)l * 2048 * 128, bf1 + l * 2048,
                                    wf2b + (size_t)l * 128 * 2048, bf2v + l * 128,
                                    l2s + l * 128, l2b + l * 128);
  }
  k_mean<<<768, 256, 0, stream>>>(zb, hbuf);
  k_head<<<768, 128, 0, stream>>>(hbuf, w1, b1, w2, b2, h2);
  k_finalize<<<768, 128, 0, stream>>>(h2, w3, b3, nrm, out);
  k_infonce<<<256, 256, 0, stream>>>(nrm, partial);
  k_loss<<<1, 256, 0, stream>>>(partial, out);
}

// Round 2
// 1347.478 us; speedup vs baseline: 1.4027x; 1.4027x over previous
//
#include <hip/hip_runtime.h>
#include <stdint.h>

typedef unsigned short u16;
typedef unsigned int   u32;
typedef unsigned long long u64;
typedef __bf16 bf16x8 __attribute__((ext_vector_type(8)));
typedef float  f32x4  __attribute__((ext_vector_type(4)));

#define LN_EPS 1e-5f
#define LSEQ   256
#define DM     128
#define B3     768
#define MTOT   196608
#define NQKV   384
#define FFD    2048

__device__ __forceinline__ u16 f2bf(float f) {
  u32 u = __builtin_bit_cast(u32, f);
  u += 0x7FFFu + ((u >> 16) & 1u);
  return (u16)(u >> 16);
}
__device__ __forceinline__ float bf2f(u16 h) {
  u32 u = ((u32)h) << 16;
  return __builtin_bit_cast(float, u);
}
__device__ __forceinline__ bf16x8 ld_bf8(const u16* p) {
  return __builtin_bit_cast(bf16x8, *(const uint4*)p);
}
__device__ __forceinline__ f32x4 mfma16(bf16x8 a, bf16x8 b, f32x4 c) {
  return __builtin_amdgcn_mfma_f32_16x16x32_bf16(a, b, c, 0, 0, 0);
}
// async global->LDS, 16B per lane; lds dest must be wave-uniform base + lane*16
__device__ __forceinline__ void gload16(const u16* g, u16* l) {
  __builtin_amdgcn_global_load_lds(
      (__attribute__((address_space(1))) void*)(uintptr_t)g,
      (__attribute__((address_space(3))) void*)(uintptr_t)l, 16, 0, 0);
}
__device__ __forceinline__ u64 pack4bf(float a, float b, float c, float d) {
  return (u64)f2bf(a) | ((u64)f2bf(b) << 16) | ((u64)f2bf(c) << 32) | ((u64)f2bf(d) << 48);
}

// ---------------- f32 -> bf16 weight conversion ----------------
__global__ __launch_bounds__(256) void k_cvt(const float* src, u16* dst, int n8) {
  int gid = blockIdx.x * 256 + threadIdx.x;
  if (gid >= n8) return;
  const float* s = src + gid * 8;
  union { u16 o[8]; uint4 v; } t;
#pragma unroll
  for (int j = 0; j < 8; ++j) t.o[j] = f2bf(s[j]);
  *(uint4*)(dst + (size_t)gid * 8) = t.v;
}

// ---------------- embed: zb[row][d] = x*w0[d] + b0[d] (bf16) ----------------
__global__ __launch_bounds__(256) void k_embed(const float* x, const float* xp, const float* xn,
                                               const float* w0, const float* b0, u16* zb) {
  int gid = blockIdx.x * 256 + threadIdx.x; // M*16
  int row = gid >> 4;
  int oct = gid & 15;
  int br  = row >> 16;
  int loc = row & 65535;
  const float* xs = br == 0 ? x : (br == 1 ? xp : xn);
  float xv = xs[loc];
  int d0 = oct * 8;
  union { u16 o[8]; uint4 v; } t;
#pragma unroll
  for (int j = 0; j < 8; ++j) t.o[j] = f2bf(xv * w0[d0 + j] + b0[d0 + j]);
  *(uint4*)(zb + (size_t)row * DM + d0) = t.v;
}

// ---------------- QKV GEMM: out[m][n] = zb[m]·Wqkv[n] + bias (bf16 out) -----
__global__ __launch_bounds__(256) void k_qkv(const u16* zb, const u16* wt, const float* bias, u16* out) {
  __shared__ union {
    struct { u16 A[16384]; u16 B[16384]; } s;
    u16 bounce[128 * 136];
  } u;
  int tid = threadIdx.x;
  int m0 = blockIdx.x * 128;
  int n0 = blockIdx.y * 128;
#pragma unroll
  for (int p = 0; p < 8; ++p) {
    int row = p * 16 + (tid >> 4);
    int gs = (tid & 15) ^ (row & 7);
    gload16(wt + (u64)(n0 + row) * 128 + gs * 8, u.s.A + p * 2048 + tid * 8);
  }
#pragma unroll
  for (int p = 0; p < 8; ++p) {
    int row = p * 16 + (tid >> 4);
    int gs = (tid & 15) ^ (row & 7);
    gload16(zb + (u64)(m0 + row) * 128 + gs * 8, u.s.B + p * 2048 + tid * 8);
  }
  __syncthreads();

  int lane = tid & 63, wv = tid >> 6;
  int l15 = lane & 15, g = lane >> 4;
  int wn = wv & 1, wm = wv >> 1;
  f32x4 acc[4][4] = {};
#pragma unroll
  for (int ks = 0; ks < 4; ++ks) {
    bf16x8 a[4], b[4];
#pragma unroll
    for (int i = 0; i < 4; ++i) {
      int row = wn * 64 + i * 16 + l15;
      int gz = (ks * 4 + g) ^ (row & 7);
      a[i] = ld_bf8(u.s.A + row * 128 + gz * 8);
    }
#pragma unroll
    for (int j = 0; j < 4; ++j) {
      int row = wm * 64 + j * 16 + l15;
      int gz = (ks * 4 + g) ^ (row & 7);
      b[j] = ld_bf8(u.s.B + row * 128 + gz * 8);
    }
#pragma unroll
    for (int i = 0; i < 4; ++i)
#pragma unroll
      for (int j = 0; j < 4; ++j) acc[i][j] = mfma16(a[i], b[j], acc[i][j]);
  }
  float bv[4][4];
#pragma unroll
  for (int i = 0; i < 4; ++i)
    *(f32x4*)bv[i] = *(const f32x4*)(bias + n0 + wn * 64 + i * 16 + g * 4);
  __syncthreads(); // A/B dead -> bounce
#pragma unroll
  for (int i = 0; i < 4; ++i) {
    int nq = wn * 64 + i * 16 + g * 4;
#pragma unroll
    for (int j = 0; j < 4; ++j) {
      int m = wm * 64 + j * 16 + l15;
      u64 pk = pack4bf(acc[i][j][0] + bv[i][0], acc[i][j][1] + bv[i][1],
                       acc[i][j][2] + bv[i][2], acc[i][j][3] + bv[i][3]);
      *(u64*)(u.bounce + m * 136 + nq) = pk;
    }
  }
  __syncthreads();
  {
    int row = tid >> 1, half = tid & 1;
    const u16* src = u.bounce + row * 136 + half * 64;
    u16* dst = out + (u64)(m0 + row) * NQKV + n0 + half * 64;
#pragma unroll
    for (int q = 0; q < 8; ++q) *(uint4*)(dst + q * 8) = *(const uint4*)(src + q * 8);
  }
}

// ---------------- attention: per (seq,head) block ----------------
__global__ __launch_bounds__(256) void k_attn(const u16* qkv, const unsigned char* mk0,
                                              const unsigned char* mk1, const unsigned char* mk2,
                                              u16* attno) {
  __shared__ u16 VT[32 * 264];
  __shared__ u16 P[4][64 * 72];
  __shared__ float pen[256];
  int tid = threadIdx.x;
  int bh = blockIdx.x;
  int bb = bh >> 2, h = bh & 3;
  {
    int br = bb >> 8, loc = bb & 255;
    const unsigned char* mp = br == 0 ? mk0 : (br == 1 ? mk1 : mk2);
    pen[tid] = mp[loc * 256 + tid] ? -1e9f : 0.0f;
  }
  {
    const u16* vsrc = qkv + (u64)(bb * 256 + tid) * NQKV + 256 + h * 32;
    u16 tmp[32];
    *(uint4*)(tmp) = *(const uint4*)vsrc;
    *(uint4*)(tmp + 8) = *(const uint4*)(vsrc + 8);
    *(uint4*)(tmp + 16) = *(const uint4*)(vsrc + 16);
    *(uint4*)(tmp + 24) = *(const uint4*)(vsrc + 24);
#pragma unroll
    for (int d = 0; d < 32; ++d) VT[d * 264 + tid] = tmp[d];
  }
  __syncthreads();

  int lane = tid & 63, wv = tid >> 6;
  int l15 = lane & 15, g = lane >> 4;
  const float scale = 0.17677669529663687f;

  bf16x8 qf[4];
#pragma unroll
  for (int j = 0; j < 4; ++j)
    qf[j] = ld_bf8(qkv + (u64)(bb * 256 + wv * 64 + j * 16 + l15) * NQKV + h * 32 + g * 8);
  bf16x8 kf[16];
#pragma unroll
  for (int kb = 0; kb < 16; ++kb)
    kf[kb] = ld_bf8(qkv + (u64)(bb * 256 + kb * 16 + l15) * NQKV + 128 + h * 32 + g * 8);

  f32x4 accO[2][4] = {};
  float lpart[4] = {0.f, 0.f, 0.f, 0.f};
  u16* Pw = &P[wv][0];
  f32x4 zf = {0.f, 0.f, 0.f, 0.f};

#pragma unroll
  for (int t = 0; t < 4; ++t) {
    f32x4 pq[4];
#pragma unroll
    for (int i = 0; i < 4; ++i) pq[i] = *(const f32x4*)(pen + t * 64 + i * 16 + g * 4);
#pragma unroll
    for (int jq = 0; jq < 4; ++jq) {
      f32x4 s[4];
#pragma unroll
      for (int i = 0; i < 4; ++i) s[i] = mfma16(kf[t * 4 + i], qf[jq], zf);
#pragma unroll
      for (int i = 0; i < 4; ++i) {
        float p0 = __expf(fmaf(s[i][0], scale, pq[i][0]));
        float p1 = __expf(fmaf(s[i][1], scale, pq[i][1]));
        float p2 = __expf(fmaf(s[i][2], scale, pq[i][2]));
        float p3 = __expf(fmaf(s[i][3], scale, pq[i][3]));
        lpart[jq] += (p0 + p1) + (p2 + p3);
        *(u64*)(Pw + (jq * 16 + l15) * 72 + i * 16 + g * 4) = pack4bf(p0, p1, p2, p3);
      }
    }
    __syncthreads();
#pragma unroll
    for (int ks = 0; ks < 2; ++ks) {
      bf16x8 va[2], pb[4];
#pragma unroll
      for (int i = 0; i < 2; ++i)
        va[i] = ld_bf8(VT + (i * 16 + l15) * 264 + t * 64 + ks * 32 + g * 8);
#pragma unroll
      for (int jq = 0; jq < 4; ++jq)
        pb[jq] = ld_bf8(Pw + (jq * 16 + l15) * 72 + ks * 32 + g * 8);
#pragma unroll
      for (int i = 0; i < 2; ++i)
#pragma unroll
        for (int jq = 0; jq < 4; ++jq) accO[i][jq] = mfma16(va[i], pb[jq], accO[i][jq]);
    }
    __syncthreads();
  }
#pragma unroll
  for (int jq = 0; jq < 4; ++jq) {
    float v = lpart[jq];
    v += __shfl_xor(v, 16);
    v += __shfl_xor(v, 32);
    lpart[jq] = 1.0f / v;
  }
#pragma unroll
  for (int i = 0; i < 2; ++i)
#pragma unroll
    for (int jq = 0; jq < 4; ++jq) {
      int q = wv * 64 + jq * 16 + l15;
      float li = lpart[jq];
      u64 pk = pack4bf(accO[i][jq][0] * li, accO[i][jq][1] * li,
                       accO[i][jq][2] * li, accO[i][jq][3] * li);
      *(u64*)(attno + ((u64)(bb * 4 + h) * 256 + q) * 32 + i * 16 + g * 4) = pk;
    }
}

// ---------------- O-proj + bias + residual + LN1 (in-place zb) ----------------
__global__ __launch_bounds__(256) void k_oln(const u16* attno, const u16* wt, const float* bias,
                                             const float* lns, const float* lnb, u16* zb) {
  __shared__ union {
    struct { u16 A[16384]; u16 B[16384]; } s;
    float bounce[64 * 132];
  } u;
  int tid = threadIdx.x;
  int m0 = blockIdx.x * 128;
#pragma unroll
  for (int p = 0; p < 8; ++p) {
    int row = p * 16 + (tid >> 4);
    int gs = (tid & 15) ^ (row & 7);
    gload16(wt + (u64)row * 128 + gs * 8, u.s.A + p * 2048 + tid * 8);
  }
  int bb = m0 >> 8, lbase = m0 & 255;
#pragma unroll
  for (int p = 0; p < 8; ++p) {
    int row = p * 16 + (tid >> 4);
    int gs = (tid & 15) ^ (row & 7);
    int hh = gs >> 2, off = (gs & 3) * 8;
    gload16(attno + ((u64)(bb * 4 + hh) * 256 + lbase + row) * 32 + off,
            u.s.B + p * 2048 + tid * 8);
  }
  __syncthreads();

  int lane = tid & 63, wv = tid >> 6;
  int l15 = lane & 15, g = lane >> 4;
  int wn = wv & 1, wm = wv >> 1;
  f32x4 acc[4][4] = {};
#pragma unroll
  for (int ks = 0; ks < 4; ++ks) {
    bf16x8 a[4], b[4];
#pragma unroll
    for (int i = 0; i < 4; ++i) {
      int row = wn * 64 + i * 16 + l15;
      int gz = (ks * 4 + g) ^ (row & 7);
      a[i] = ld_bf8(u.s.A + row * 128 + gz * 8);
    }
#pragma unroll
    for (int j = 0; j < 4; ++j) {
      int row = wm * 64 + j * 16 + l15;
      int gz = (ks * 4 + g) ^ (row & 7);
      b[j] = ld_bf8(u.s.B + row * 128 + gz * 8);
    }
#pragma unroll
    for (int i = 0; i < 4; ++i)
#pragma unroll
      for (int j = 0; j < 4; ++j) acc[i][j] = mfma16(a[i], b[j], acc[i][j]);
  }
  for (int ph = 0; ph < 2; ++ph) {
    __syncthreads();
    if (wm == ph) {
#pragma unroll
      for (int i = 0; i < 4; ++i)
#pragma unroll
        for (int j = 0; j < 4; ++j) {
          int ml = j * 16 + l15;
          int nq = wn * 64 + i * 16 + g * 4;
          *(f32x4*)(u.bounce + ml * 132 + nq) = acc[i][j];
        }
    }
    __syncthreads();
    {
      int ql = tid >> 2, q4 = tid & 3;
      int mrow = m0 + ph * 64 + ql;
      const u16* zrow = zb + (u64)mrow * 128 + q4 * 32;
      float v[32];
      float s = 0.f, s2 = 0.f;
#pragma unroll
      for (int c = 0; c < 32; ++c) {
        float val = u.bounce[ql * 132 + q4 * 32 + c] + bias[q4 * 32 + c] + bf2f(zrow[c]);
        v[c] = val; s += val; s2 += val * val;
      }
      s += __shfl_xor(s, 1);  s += __shfl_xor(s, 2);
      s2 += __shfl_xor(s2, 1); s2 += __shfl_xor(s2, 2);
      float mean = s * (1.0f / 128.0f);
      float var = s2 * (1.0f / 128.0f) - mean * mean;
      float rstd = rsqrtf(var + LN_EPS);
      union { u16 o[32]; uint4 q[4]; } t;
#pragma unroll
      for (int c = 0; c < 32; ++c)
        t.o[c] = f2bf((v[c] - mean) * rstd * lns[q4 * 32 + c] + lnb[q4 * 32 + c]);
      u16* dst = zb + (u64)mrow * 128 + q4 * 32;
#pragma unroll
      for (int q = 0; q < 4; ++q) *(uint4*)(dst + q * 8) = t.q[q];
    }
  }
}

// ---------------- fused FF v2: per-wave q-ownership + W double-buffer -------
// wave wv owns q rows [m0+wv*32, +32). H1 slice is wave-private (no barrier
// between gemm1 and gemm2). One __syncthreads per chunk: drains stage(c+1)
// (issued a full chunk earlier) and fences W buffer reuse.
__global__ __launch_bounds__(256, 2) void k_ffn(u16* zb, const u16* w1, const float* b1,
                                                const u16* w2, const float* b2,
                                                const float* lns, const float* lnb) {
  __shared__ u16 W1b[2][8192]; // 64 ff-rows x 128, granule-XOR by (row&7)
  __shared__ u16 W2b[2][8192]; // 128 d-rows x 64, granule-XOR by (row&7)
  __shared__ u16 H1s[4][2048]; // per-wave 32 q-rows x 64 ff, byte ^ ((q&7)<<4)
  int tid = threadIdx.x;
  int m0 = blockIdx.x * 128;
  int lane = tid & 63, wv = tid >> 6;
  int l15 = lane & 15, g = lane >> 4;
  int qb = m0 + wv * 32;

  // z fragments for this wave's 32 rows (reused for all 32 chunks)
  bf16x8 az[2][4];
#pragma unroll
  for (int j = 0; j < 2; ++j)
#pragma unroll
    for (int ks = 0; ks < 4; ++ks)
      az[j][ks] = ld_bf8(zb + (u64)(qb + j * 16 + l15) * 128 + ks * 32 + g * 8);

  // prologue: stage chunk 0
  {
#pragma unroll
    for (int p = 0; p < 4; ++p) {
      int row = p * 16 + (tid >> 4);
      int gs = (tid & 15) ^ (row & 7);
      gload16(w1 + (u64)row * 128 + gs * 8, W1b[0] + p * 2048 + tid * 8);
    }
#pragma unroll
    for (int p = 0; p < 4; ++p) {
      int row = p * 32 + (tid >> 3);
      int gs = (tid & 7) ^ (row & 7);
      gload16(w2 + (u64)row * FFD + gs * 8, W2b[0] + p * 2048 + tid * 8);
    }
  }
  __syncthreads();

  f32x4 acc2[8][2] = {};
  char* Hw = (char*)&H1s[wv][0];

  for (int c = 0; c < 32; ++c) {
    int cur = c & 1;
    // prefetch chunk c+1 into the other buffer (stays in flight across compute)
    if (c < 31) {
      const u16* w1n = w1 + (u64)(c + 1) * 64 * 128;
      const u16* w2n = w2 + (u64)(c + 1) * 64;
      u16* d1 = W1b[cur ^ 1];
      u16* d2 = W2b[cur ^ 1];
#pragma unroll
      for (int p = 0; p < 4; ++p) {
        int row = p * 16 + (tid >> 4);
        int gs = (tid & 15) ^ (row & 7);
        gload16(w1n + (u64)row * 128 + gs * 8, d1 + p * 2048 + tid * 8);
      }
#pragma unroll
      for (int p = 0; p < 4; ++p) {
        int row = p * 32 + (tid >> 3);
        int gs = (tid & 7) ^ (row & 7);
        gload16(w2n + (u64)row * FFD + gs * 8, d2 + p * 2048 + tid * 8);
      }
    }
    const u16* W1c = W1b[cur];
    const u16* W2c = W2b[cur];

    // ---- gemm1: a1[i][j] = W1chunk(ff=i*16+g*4+r) x z(q=j*16+l15) ----
    f32x4 a1[4][2] = {};
#pragma unroll
    for (int ks = 0; ks < 4; ++ks) {
      bf16x8 af[4];
#pragma unroll
      for (int i = 0; i < 4; ++i) {
        int row = i * 16 + l15;
        int gz = (ks * 4 + g) ^ (row & 7);
        af[i] = ld_bf8(W1c + row * 128 + gz * 8);
      }
#pragma unroll
      for (int i = 0; i < 4; ++i)
#pragma unroll
        for (int j = 0; j < 2; ++j) a1[i][j] = mfma16(af[i], az[j][ks], a1[i][j]);
    }
    // ---- bias + relu -> wave-private H1 (swizzled) ----
#pragma unroll
    for (int i = 0; i < 4; ++i) {
      f32x4 bq = *(const f32x4*)(b1 + c * 64 + i * 16 + g * 4);
#pragma unroll
      for (int j = 0; j < 2; ++j) {
        int q = j * 16 + l15;
        float t0 = a1[i][j][0] + bq[0]; t0 = t0 > 0.f ? t0 : 0.f;
        float t1 = a1[i][j][1] + bq[1]; t1 = t1 > 0.f ? t1 : 0.f;
        float t2 = a1[i][j][2] + bq[2]; t2 = t2 > 0.f ? t2 : 0.f;
        float t3 = a1[i][j][3] + bq[3]; t3 = t3 > 0.f ? t3 : 0.f;
        int off = (q * 128 + i * 32 + g * 8) ^ ((q & 7) << 4);
        *(u64*)(Hw + off) = pack4bf(t0, t1, t2, t3);
      }
    }
    // ---- gemm2: acc2[i][j] += W2chunk(d=i*16+g*4+r) x H1(q=j*16+l15) ----
#pragma unroll
    for (int ks = 0; ks < 2; ++ks) {
      bf16x8 pb[2];
#pragma unroll
      for (int j = 0; j < 2; ++j) {
        int q = j * 16 + l15;
        int off = (q * 128 + ks * 64 + g * 16) ^ ((q & 7) << 4);
        pb[j] = ld_bf8((const u16*)(Hw + off));
      }
#pragma unroll
      for (int i = 0; i < 8; ++i) {
        int row = i * 16 + l15;
        int gz = (ks * 4 + g) ^ (row & 7);
        bf16x8 wf = ld_bf8(W2c + row * 64 + gz * 8);
#pragma unroll
        for (int j = 0; j < 2; ++j) acc2[i][j] = mfma16(wf, pb[j], acc2[i][j]);
      }
    }
    __syncthreads(); // drains vmcnt(0): stage(c+1) landed; buf[cur] reads done
  }

  // ---- epilogue: bias + residual + LN2, all in registers ----
  float s[2] = {0.f, 0.f}, s2[2] = {0.f, 0.f};
#pragma unroll
  for (int i = 0; i < 8; ++i) {
    f32x4 bq = *(const f32x4*)(b2 + i * 16 + g * 4);
#pragma unroll
    for (int j = 0; j < 2; ++j) {
      int q = qb + j * 16 + l15;
      u64 zo = *(const u64*)(zb + (u64)q * 128 + i * 16 + g * 4);
#pragma unroll
      for (int r = 0; r < 4; ++r) {
        float val = acc2[i][j][r] + bq[r] + bf2f((u16)(zo >> (16 * r)));
        acc2[i][j][r] = val;
        s[j] += val; s2[j] += val * val;
      }
    }
  }
  float mval[2], rstd[2];
#pragma unroll
  for (int j = 0; j < 2; ++j) {
    float a = s[j], b = s2[j];
    a += __shfl_xor(a, 16); a += __shfl_xor(a, 32);
    b += __shfl_xor(b, 16); b += __shfl_xor(b, 32);
    float mean = a * (1.0f / 128.0f);
    float var = b * (1.0f / 128.0f) - mean * mean;
    mval[j] = mean;
    rstd[j] = rsqrtf(var + LN_EPS);
  }
#pragma unroll
  for (int i = 0; i < 8; ++i) {
    f32x4 ls = *(const f32x4*)(lns + i * 16 + g * 4);
    f32x4 lb = *(const f32x4*)(lnb + i * 16 + g * 4);
#pragma unroll
    for (int j = 0; j < 2; ++j) {
      int q = qb + j * 16 + l15;
      u64 pk = pack4bf((acc2[i][j][0] - mval[j]) * rstd[j] * ls[0] + lb[0],
                       (acc2[i][j][1] - mval[j]) * rstd[j] * ls[1] + lb[1],
                       (acc2[i][j][2] - mval[j]) * rstd[j] * ls[2] + lb[2],
                       (acc2[i][j][3] - mval[j]) * rstd[j] * ls[3] + lb[3]);
      *(u64*)(zb + (u64)q * 128 + i * 16 + g * 4) = pk;
    }
  }
}

// ---------------- mean over seq ----------------
__global__ __launch_bounds__(256) void k_mean(const u16* zb, float* h) {
  __shared__ float part[4][128];
  int tid = threadIdx.x, bb = blockIdx.x;
  int d2 = tid & 63, lg = tid >> 6;
  float s0 = 0.f, s1 = 0.f;
  for (int li = 0; li < 64; ++li) {
    int l = lg * 64 + li;
    u32 v = *(const u32*)(zb + (u64)(bb * 256 + l) * 128 + d2 * 2);
    s0 += bf2f((u16)(v & 0xffffu));
    s1 += bf2f((u16)(v >> 16));
  }
  part[lg][d2 * 2] = s0;
  part[lg][d2 * 2 + 1] = s1;
  __syncthreads();
  if (tid < 128) {
    float s = part[0][tid] + part[1][tid] + part[2][tid] + part[3][tid];
    h[bb * 128 + tid] = s * (1.0f / 256.0f);
  }
}

// ---------------- head: tanh(tanh(h W1^T + b1) W2^T + b2) ----------------
__global__ __launch_bounds__(128) void k_head(const float* h, const float* w1, const float* b1,
                                              const float* w2, const float* b2, float* h2) {
  __shared__ float r0[128], r1[128];
  int tid = threadIdx.x, bb = blockIdx.x;
  r0[tid] = h[bb * 128 + tid];
  __syncthreads();
  float s = b1[tid];
  const float* wr = w1 + tid * 128;
  for (int k = 0; k < 128; ++k) s += r0[k] * wr[k];
  r1[tid] = tanhf(s);
  __syncthreads();
  float s2 = b2[tid];
  const float* wr2 = w2 + tid * 128;
  for (int k = 0; k < 128; ++k) s2 += r1[k] * wr2[k];
  h2[bb * 128 + tid] = tanhf(s2);
}

// ---------------- finalize ----------------
__global__ __launch_bounds__(128) void k_finalize(const float* h2, const float* w3, const float* b3,
                                                  float* nrm, float* out) {
  __shared__ float row[128];
  __shared__ float red[2];
  __shared__ float lg[3];
  int tid = threadIdx.x, i = blockIdx.x;
  float v = h2[i * 128 + tid];
  row[tid] = v;
  float sq = v * v;
#pragma unroll
  for (int o = 32; o; o >>= 1) sq += __shfl_xor(sq, o);
  if ((tid & 63) == 0) red[tid >> 6] = sq;
  __syncthreads();
  float rinv = rsqrtf(red[0] + red[1]);
  float nv = v * rinv;
  nrm[i * 128 + tid] = nv;
  int br = i >> 8, loc = i & 255;
  if (br == 0)      out[loc * 128 + tid] = nv;
  else if (br == 1) out[32768 + loc * 128 + tid] = v;
  else              out[65536 + loc * 128 + tid] = v;
  if (br == 0) {
    if (tid < 3) {
      float s = b3[tid];
      const float* wr = w3 + tid * 128;
      for (int k = 0; k < 128; ++k) s += row[k] * wr[k];
      lg[tid] = s;
    }
    __syncthreads();
    if (tid == 0) {
      float m = fmaxf(lg[0], fmaxf(lg[1], lg[2]));
      float e0 = __expf(lg[0] - m), e1 = __expf(lg[1] - m), e2 = __expf(lg[2] - m);
      float si = 1.0f / (e0 + e1 + e2);
      out[98304 + loc * 3 + 0] = e0 * si;
      out[98304 + loc * 3 + 1] = e1 * si;
      out[98304 + loc * 3 + 2] = e2 * si;
    }
  }
}

// ---------------- InfoNCE per-row partial ----------------
__global__ __launch_bounds__(256) void k_infonce(const float* nrm, float* partial) {
  __shared__ float nbi[128];
  __shared__ float red[8];
  __shared__ float posv;
  int tid = threadIdx.x, i = blockIdx.x;
  if (tid < 128) nbi[tid] = nrm[i * 128 + tid];
  __syncthreads();
  const float* a = nrm + (u64)(256 + tid) * 128;
  const float* b = nrm + (u64)(512 + tid) * 128;
  float s1 = 0.f, s2 = 0.f;
  for (int k = 0; k < 128; ++k) { s1 += nbi[k] * a[k]; s2 += nbi[k] * b[k]; }
  s1 *= 20.0f; s2 *= 20.0f;
  if (tid == i) posv = s1;
  float m = fmaxf(s1, s2);
#pragma unroll
  for (int o = 32; o; o >>= 1) m = fmaxf(m, __shfl_xor(m, o));
  if ((tid & 63) == 0) red[tid >> 6] = m;
  __syncthreads();
  float M = fmaxf(fmaxf(red[0], red[1]), fmaxf(red[2], red[3]));
  float e = __expf(s1 - M) + __expf(s2 - M);
#pragma unroll
  for (int o = 32; o; o >>= 1) e += __shfl_xor(e, o);
  if ((tid & 63) == 0) red[4 + (tid >> 6)] = e;
  __syncthreads();
  if (tid == 0) {
    float S = red[4] + red[5] + red[6] + red[7];
    partial[i] = logf(S) + M - posv;
  }
}

__global__ __launch_bounds__(256) void k_loss(const float* partial, float* out) {
  int tid = threadIdx.x;
  float v = partial[tid];
#pragma unroll
  for (int o = 32; o; o >>= 1) v += __shfl_xor(v, o);
  __shared__ float red[4];
  if ((tid & 63) == 0) red[tid >> 6] = v;
  __syncthreads();
  if (tid == 0) out[99072] = (red[0] + red[1] + red[2] + red[3]) * (1.0f / 256.0f);
}

extern "C" void kernel_launch(void* const* d_in, const int* in_sizes, int n_in,
                              void* d_out, int out_size, void* d_ws, size_t ws_size,
                              hipStream_t stream) {
  const float* x   = (const float*)d_in[0];
  const float* xp  = (const float*)d_in[1];
  const float* xn  = (const float*)d_in[2];
  const unsigned char* mk0 = (const unsigned char*)d_in[3];
  const unsigned char* mk1 = (const unsigned char*)d_in[4];
  const unsigned char* mk2 = (const unsigned char*)d_in[5];
  const float* w0   = (const float*)d_in[6];
  const float* b0   = (const float*)d_in[7];
  const float* wqkv = (const float*)d_in[8];
  const float* bqkv = (const float*)d_in[9];
  const float* wo   = (const float*)d_in[10];
  const float* bo   = (const float*)d_in[11];
  const float* wf1  = (const float*)d_in[12];
  const float* bf1  = (const float*)d_in[13];
  const float* wf2  = (const float*)d_in[14];
  const float* bf2v = (const float*)d_in[15];
  const float* l1s  = (const float*)d_in[16];
  const float* l1b  = (const float*)d_in[17];
  const float* l2s  = (const float*)d_in[18];
  const float* l2b  = (const float*)d_in[19];
  const float* w1   = (const float*)d_in[20];
  const float* b1   = (const float*)d_in[21];
  const float* w2   = (const float*)d_in[22];
  const float* b2   = (const float*)d_in[23];
  const float* w3   = (const float*)d_in[24];
  const float* b3   = (const float*)d_in[25];
  float* out = (float*)d_out;

  char* ws = (char*)d_ws;
  u16* zb    = (u16*)ws; ws += (size_t)MTOT * 128 * 2;
  u16* qkv   = (u16*)ws; ws += (size_t)MTOT * 384 * 2;
  u16* attno = (u16*)ws; ws += (size_t)MTOT * 128 * 2;
  u16* wqb   = (u16*)ws; ws += (size_t)3 * 384 * 128 * 2;
  u16* wob   = (u16*)ws; ws += (size_t)3 * 128 * 128 * 2;
  u16* wf1b  = (u16*)ws; ws += (size_t)3 * 2048 * 128 * 2;
  u16* wf2b  = (u16*)ws; ws += (size_t)3 * 128 * 2048 * 2;
  float* hbuf = (float*)ws; ws += (size_t)768 * 128 * 4;
  float* h2   = (float*)ws; ws += (size_t)768 * 128 * 4;
  float* nrm  = (float*)ws; ws += (size_t)768 * 128 * 4;
  float* partial = (float*)ws;

  k_cvt<<<72, 256, 0, stream>>>(wqkv, wqb, 3 * 384 * 128 / 8);
  k_cvt<<<24, 256, 0, stream>>>(wo, wob, 3 * 128 * 128 / 8);
  k_cvt<<<384, 256, 0, stream>>>(wf1, wf1b, 3 * 2048 * 128 / 8);
  k_cvt<<<384, 256, 0, stream>>>(wf2, wf2b, 3 * 128 * 2048 / 8);
  k_embed<<<12288, 256, 0, stream>>>(x, xp, xn, w0, b0, zb);

  for (int l = 0; l < 3; ++l) {
    k_qkv<<<dim3(1536, 3), 256, 0, stream>>>(zb, wqb + (size_t)l * 384 * 128,
                                             bqkv + l * 384, qkv);
    k_attn<<<3072, 256, 0, stream>>>(qkv, mk0, mk1, mk2, attno);
    k_oln<<<1536, 256, 0, stream>>>(attno, wob + (size_t)l * 128 * 128, bo + l * 128,
                                    l1s + l * 128, l1b + l * 128, zb);
    k_ffn<<<1536, 256, 0, stream>>>(zb, wf1b + (size_t)l * 2048 * 128, bf1 + l * 2048,
                                    wf2b + (size_t)l * 128 * 2048, bf2v + l * 128,
                                    l2s + l * 128, l2b + l * 128);
  }
  k_mean<<<768, 256, 0, stream>>>(zb, hbuf);
  k_head<<<768, 128, 0, stream>>>(hbuf, w1, b1, w2, b2, h2);
  k_finalize<<<768, 128, 0, stream>>>(h2, w3, b3, nrm, out);
  k_infonce<<<256, 256, 0, stream>>>(nrm, partial);
  k_loss<<<1, 256, 0, stream>>>(partial, out);
}

// Round 3
// 1262.940 us; speedup vs baseline: 1.4966x; 1.0669x over previous
//
#include <hip/hip_runtime.h>
#include <stdint.h>

typedef unsigned short u16;
typedef unsigned int   u32;
typedef unsigned long long u64;
typedef __bf16 bf16x8 __attribute__((ext_vector_type(8)));
typedef __bf16 bf16x4t __attribute__((ext_vector_type(4)));
typedef float  f32x4  __attribute__((ext_vector_type(4)));

#define LN_EPS 1e-5f
#define LSEQ   256
#define DM     128
#define B3     768
#define MTOT   196608
#define NQKV   384
#define FFD    2048

__device__ __forceinline__ u16 f2bf(float f) {
  __bf16 h = (__bf16)f;               // v_cvt_pk_bf16_f32 path (RNE)
  return __builtin_bit_cast(u16, h);
}
__device__ __forceinline__ float bf2f(u16 h) {
  u32 u = ((u32)h) << 16;
  return __builtin_bit_cast(float, u);
}
__device__ __forceinline__ bf16x8 ld_bf8(const u16* p) {
  return __builtin_bit_cast(bf16x8, *(const uint4*)p);
}
__device__ __forceinline__ f32x4 mfma16(bf16x8 a, bf16x8 b, f32x4 c) {
  return __builtin_amdgcn_mfma_f32_16x16x32_bf16(a, b, c, 0, 0, 0);
}
// async global->LDS, 16B per lane; lds dest must be wave-uniform base + lane*16
__device__ __forceinline__ void gload16(const u16* g, u16* l) {
  __builtin_amdgcn_global_load_lds(
      (__attribute__((address_space(1))) void*)(uintptr_t)g,
      (__attribute__((address_space(3))) void*)(uintptr_t)l, 16, 0, 0);
}
__device__ __forceinline__ u64 pack4bf(float a, float b, float c, float d) {
  bf16x4t t;
  t[0] = (__bf16)a; t[1] = (__bf16)b; t[2] = (__bf16)c; t[3] = (__bf16)d;
  return __builtin_bit_cast(u64, t);
}

// ---------------- f32 -> bf16 weight conversion ----------------
__global__ __launch_bounds__(256) void k_cvt(const float* src, u16* dst, int n8) {
  int gid = blockIdx.x * 256 + threadIdx.x;
  if (gid >= n8) return;
  const float* s = src + gid * 8;
  union { u16 o[8]; uint4 v; } t;
#pragma unroll
  for (int j = 0; j < 8; ++j) t.o[j] = f2bf(s[j]);
  *(uint4*)(dst + (size_t)gid * 8) = t.v;
}

// ---------------- embed: zb[row][d] = x*w0[d] + b0[d] (bf16) ----------------
__global__ __launch_bounds__(256) void k_embed(const float* x, const float* xp, const float* xn,
                                               const float* w0, const float* b0, u16* zb) {
  int gid = blockIdx.x * 256 + threadIdx.x; // M*16
  int row = gid >> 4;
  int oct = gid & 15;
  int br  = row >> 16;
  int loc = row & 65535;
  const float* xs = br == 0 ? x : (br == 1 ? xp : xn);
  float xv = xs[loc];
  int d0 = oct * 8;
  union { u16 o[8]; uint4 v; } t;
#pragma unroll
  for (int j = 0; j < 8; ++j) t.o[j] = f2bf(xv * w0[d0 + j] + b0[d0 + j]);
  *(uint4*)(zb + (size_t)row * DM + d0) = t.v;
}

// ---------------- QKV GEMM: out[m][n] = zb[m]·Wqkv[n] + bias (bf16 out) -----
__global__ __launch_bounds__(256) void k_qkv(const u16* zb, const u16* wt, const float* bias, u16* out) {
  __shared__ union {
    struct { u16 A[16384]; u16 B[16384]; } s;
    u16 bounce[128 * 136];
  } u;
  int tid = threadIdx.x;
  int m0 = blockIdx.x * 128;
  int n0 = blockIdx.y * 128;
#pragma unroll
  for (int p = 0; p < 8; ++p) {
    int row = p * 16 + (tid >> 4);
    int gs = (tid & 15) ^ (row & 7);
    gload16(wt + (u64)(n0 + row) * 128 + gs * 8, u.s.A + p * 2048 + tid * 8);
  }
#pragma unroll
  for (int p = 0; p < 8; ++p) {
    int row = p * 16 + (tid >> 4);
    int gs = (tid & 15) ^ (row & 7);
    gload16(zb + (u64)(m0 + row) * 128 + gs * 8, u.s.B + p * 2048 + tid * 8);
  }
  __syncthreads();

  int lane = tid & 63, wv = tid >> 6;
  int l15 = lane & 15, g = lane >> 4;
  int wn = wv & 1, wm = wv >> 1;
  f32x4 acc[4][4] = {};
#pragma unroll
  for (int ks = 0; ks < 4; ++ks) {
    bf16x8 a[4], b[4];
#pragma unroll
    for (int i = 0; i < 4; ++i) {
      int row = wn * 64 + i * 16 + l15;
      int gz = (ks * 4 + g) ^ (row & 7);
      a[i] = ld_bf8(u.s.A + row * 128 + gz * 8);
    }
#pragma unroll
    for (int j = 0; j < 4; ++j) {
      int row = wm * 64 + j * 16 + l15;
      int gz = (ks * 4 + g) ^ (row & 7);
      b[j] = ld_bf8(u.s.B + row * 128 + gz * 8);
    }
#pragma unroll
    for (int i = 0; i < 4; ++i)
#pragma unroll
      for (int j = 0; j < 4; ++j) acc[i][j] = mfma16(a[i], b[j], acc[i][j]);
  }
  float bv[4][4];
#pragma unroll
  for (int i = 0; i < 4; ++i)
    *(f32x4*)bv[i] = *(const f32x4*)(bias + n0 + wn * 64 + i * 16 + g * 4);
  __syncthreads(); // A/B dead -> bounce
#pragma unroll
  for (int i = 0; i < 4; ++i) {
    int nq = wn * 64 + i * 16 + g * 4;
#pragma unroll
    for (int j = 0; j < 4; ++j) {
      int m = wm * 64 + j * 16 + l15;
      u64 pk = pack4bf(acc[i][j][0] + bv[i][0], acc[i][j][1] + bv[i][1],
                       acc[i][j][2] + bv[i][2], acc[i][j][3] + bv[i][3]);
      *(u64*)(u.bounce + m * 136 + nq) = pk;
    }
  }
  __syncthreads();
  {
    int row = tid >> 1, half = tid & 1;
    const u16* src = u.bounce + row * 136 + half * 64;
    u16* dst = out + (u64)(m0 + row) * NQKV + n0 + half * 64;
#pragma unroll
    for (int q = 0; q < 8; ++q) *(uint4*)(dst + q * 8) = *(const uint4*)(src + q * 8);
  }
}

// ---------------- attention: per (seq,head) block ----------------
// S^T = K·Q^T -> exp2 (scores tiny, mask via -1e9 penalty) -> P (wave-private
// LDS, no block barrier needed) -> O^T = VT·P^T
__global__ __launch_bounds__(256) void k_attn(const u16* qkv, const unsigned char* mk0,
                                              const unsigned char* mk1, const unsigned char* mk2,
                                              u16* attno) {
  __shared__ u16 VT[32 * 264];
  __shared__ u16 P[4][64 * 72];
  __shared__ float pen[256];
  int tid = threadIdx.x;
  int bh = blockIdx.x;
  int bb = bh >> 2, h = bh & 3;
  {
    int br = bb >> 8, loc = bb & 255;
    const unsigned char* mp = br == 0 ? mk0 : (br == 1 ? mk1 : mk2);
    pen[tid] = mp[loc * 256 + tid] ? -1e9f : 0.0f;
  }
  {
    const u16* vsrc = qkv + (u64)(bb * 256 + tid) * NQKV + 256 + h * 32;
    u16 tmp[32];
    *(uint4*)(tmp) = *(const uint4*)vsrc;
    *(uint4*)(tmp + 8) = *(const uint4*)(vsrc + 8);
    *(uint4*)(tmp + 16) = *(const uint4*)(vsrc + 16);
    *(uint4*)(tmp + 24) = *(const uint4*)(vsrc + 24);
#pragma unroll
    for (int d = 0; d < 32; ++d) VT[d * 264 + tid] = tmp[d];
  }
  __syncthreads();

  int lane = tid & 63, wv = tid >> 6;
  int l15 = lane & 15, g = lane >> 4;
  const float scale2 = 0.25503492149314874f; // 1/sqrt(32) * log2(e)

  bf16x8 qf[4];
#pragma unroll
  for (int j = 0; j < 4; ++j)
    qf[j] = ld_bf8(qkv + (u64)(bb * 256 + wv * 64 + j * 16 + l15) * NQKV + h * 32 + g * 8);
  bf16x8 kf[16];
#pragma unroll
  for (int kb = 0; kb < 16; ++kb)
    kf[kb] = ld_bf8(qkv + (u64)(bb * 256 + kb * 16 + l15) * NQKV + 128 + h * 32 + g * 8);

  f32x4 accO[2][4] = {};
  float lpart[4] = {0.f, 0.f, 0.f, 0.f};
  u16* Pw = &P[wv][0];
  f32x4 zf = {0.f, 0.f, 0.f, 0.f};

#pragma unroll
  for (int t = 0; t < 4; ++t) {
    f32x4 pq[4];
#pragma unroll
    for (int i = 0; i < 4; ++i) pq[i] = *(const f32x4*)(pen + t * 64 + i * 16 + g * 4);
#pragma unroll
    for (int jq = 0; jq < 4; ++jq) {
      f32x4 s[4];
#pragma unroll
      for (int i = 0; i < 4; ++i) s[i] = mfma16(kf[t * 4 + i], qf[jq], zf);
#pragma unroll
      for (int i = 0; i < 4; ++i) {
        float p0 = __builtin_amdgcn_exp2f(fmaf(s[i][0], scale2, pq[i][0]));
        float p1 = __builtin_amdgcn_exp2f(fmaf(s[i][1], scale2, pq[i][1]));
        float p2 = __builtin_amdgcn_exp2f(fmaf(s[i][2], scale2, pq[i][2]));
        float p3 = __builtin_amdgcn_exp2f(fmaf(s[i][3], scale2, pq[i][3]));
        lpart[jq] += (p0 + p1) + (p2 + p3);
        *(u64*)(Pw + (jq * 16 + l15) * 72 + i * 16 + g * 4) = pack4bf(p0, p1, p2, p3);
      }
    }
    // P is wave-private: in-wave ds_write->ds_read ordering via lgkmcnt only.
#pragma unroll
    for (int ks = 0; ks < 2; ++ks) {
      bf16x8 va[2], pb[4];
#pragma unroll
      for (int i = 0; i < 2; ++i)
        va[i] = ld_bf8(VT + (i * 16 + l15) * 264 + t * 64 + ks * 32 + g * 8);
#pragma unroll
      for (int jq = 0; jq < 4; ++jq)
        pb[jq] = ld_bf8(Pw + (jq * 16 + l15) * 72 + ks * 32 + g * 8);
#pragma unroll
      for (int i = 0; i < 2; ++i)
#pragma unroll
        for (int jq = 0; jq < 4; ++jq) accO[i][jq] = mfma16(va[i], pb[jq], accO[i][jq]);
    }
  }
#pragma unroll
  for (int jq = 0; jq < 4; ++jq) {
    float v = lpart[jq];
    v += __shfl_xor(v, 16);
    v += __shfl_xor(v, 32);
    lpart[jq] = 1.0f / v;
  }
#pragma unroll
  for (int i = 0; i < 2; ++i)
#pragma unroll
    for (int jq = 0; jq < 4; ++jq) {
      int q = wv * 64 + jq * 16 + l15;
      float li = lpart[jq];
      u64 pk = pack4bf(accO[i][jq][0] * li, accO[i][jq][1] * li,
                       accO[i][jq][2] * li, accO[i][jq][3] * li);
      *(u64*)(attno + ((u64)(bb * 4 + h) * 256 + q) * 32 + i * 16 + g * 4) = pk;
    }
}

// ---------------- O-proj + bias + residual + LN1 (in-place zb) ----------------
__global__ __launch_bounds__(256) void k_oln(const u16* attno, const u16* wt, const float* bias,
                                             const float* lns, const float* lnb, u16* zb) {
  __shared__ union {
    struct { u16 A[16384]; u16 B[16384]; } s;
    float bounce[64 * 132];
  } u;
  int tid = threadIdx.x;
  int m0 = blockIdx.x * 128;
#pragma unroll
  for (int p = 0; p < 8; ++p) {
    int row = p * 16 + (tid >> 4);
    int gs = (tid & 15) ^ (row & 7);
    gload16(wt + (u64)row * 128 + gs * 8, u.s.A + p * 2048 + tid * 8);
  }
  int bb = m0 >> 8, lbase = m0 & 255;
#pragma unroll
  for (int p = 0; p < 8; ++p) {
    int row = p * 16 + (tid >> 4);
    int gs = (tid & 15) ^ (row & 7);
    int hh = gs >> 2, off = (gs & 3) * 8;
    gload16(attno + ((u64)(bb * 4 + hh) * 256 + lbase + row) * 32 + off,
            u.s.B + p * 2048 + tid * 8);
  }
  __syncthreads();

  int lane = tid & 63, wv = tid >> 6;
  int l15 = lane & 15, g = lane >> 4;
  int wn = wv & 1, wm = wv >> 1;
  f32x4 acc[4][4] = {};
#pragma unroll
  for (int ks = 0; ks < 4; ++ks) {
    bf16x8 a[4], b[4];
#pragma unroll
    for (int i = 0; i < 4; ++i) {
      int row = wn * 64 + i * 16 + l15;
      int gz = (ks * 4 + g) ^ (row & 7);
      a[i] = ld_bf8(u.s.A + row * 128 + gz * 8);
    }
#pragma unroll
    for (int j = 0; j < 4; ++j) {
      int row = wm * 64 + j * 16 + l15;
      int gz = (ks * 4 + g) ^ (row & 7);
      b[j] = ld_bf8(u.s.B + row * 128 + gz * 8);
    }
#pragma unroll
    for (int i = 0; i < 4; ++i)
#pragma unroll
      for (int j = 0; j < 4; ++j) acc[i][j] = mfma16(a[i], b[j], acc[i][j]);
  }
  for (int ph = 0; ph < 2; ++ph) {
    __syncthreads();
    if (wm == ph) {
#pragma unroll
      for (int i = 0; i < 4; ++i)
#pragma unroll
        for (int j = 0; j < 4; ++j) {
          int ml = j * 16 + l15;
          int nq = wn * 64 + i * 16 + g * 4;
          *(f32x4*)(u.bounce + ml * 132 + nq) = acc[i][j];
        }
    }
    __syncthreads();
    {
      int ql = tid >> 2, q4 = tid & 3;
      int mrow = m0 + ph * 64 + ql;
      const u16* zrow = zb + (u64)mrow * 128 + q4 * 32;
      float v[32];
      float s = 0.f, s2 = 0.f;
#pragma unroll
      for (int c = 0; c < 32; ++c) {
        float val = u.bounce[ql * 132 + q4 * 32 + c] + bias[q4 * 32 + c] + bf2f(zrow[c]);
        v[c] = val; s += val; s2 += val * val;
      }
      s += __shfl_xor(s, 1);  s += __shfl_xor(s, 2);
      s2 += __shfl_xor(s2, 1); s2 += __shfl_xor(s2, 2);
      float mean = s * (1.0f / 128.0f);
      float var = s2 * (1.0f / 128.0f) - mean * mean;
      float rstd = rsqrtf(var + LN_EPS);
      union { u16 o[32]; uint4 q[4]; } t;
#pragma unroll
      for (int c = 0; c < 32; ++c)
        t.o[c] = f2bf((v[c] - mean) * rstd * lns[q4 * 32 + c] + lnb[q4 * 32 + c]);
      u16* dst = zb + (u64)mrow * 128 + q4 * 32;
#pragma unroll
      for (int q = 0; q < 4; ++q) *(uint4*)(dst + q * 8) = t.q[q];
    }
  }
}

// ---------------- fused FF v2: per-wave q-ownership + W double-buffer -------
__global__ __launch_bounds__(256, 2) void k_ffn(u16* zb, const u16* w1, const float* b1,
                                                const u16* w2, const float* b2,
                                                const float* lns, const float* lnb) {
  __shared__ u16 W1b[2][8192]; // 64 ff-rows x 128, granule-XOR by (row&7)
  __shared__ u16 W2b[2][8192]; // 128 d-rows x 64, granule-XOR by (row&7)
  __shared__ u16 H1s[4][2048]; // per-wave 32 q-rows x 64 ff, byte ^ ((q&7)<<4)
  int tid = threadIdx.x;
  int m0 = blockIdx.x * 128;
  int lane = tid & 63, wv = tid >> 6;
  int l15 = lane & 15, g = lane >> 4;
  int qb = m0 + wv * 32;

  bf16x8 az[2][4];
#pragma unroll
  for (int j = 0; j < 2; ++j)
#pragma unroll
    for (int ks = 0; ks < 4; ++ks)
      az[j][ks] = ld_bf8(zb + (u64)(qb + j * 16 + l15) * 128 + ks * 32 + g * 8);

  {
#pragma unroll
    for (int p = 0; p < 4; ++p) {
      int row = p * 16 + (tid >> 4);
      int gs = (tid & 15) ^ (row & 7);
      gload16(w1 + (u64)row * 128 + gs * 8, W1b[0] + p * 2048 + tid * 8);
    }
#pragma unroll
    for (int p = 0; p < 4; ++p) {
      int row = p * 32 + (tid >> 3);
      int gs = (tid & 7) ^ (row & 7);
      gload16(w2 + (u64)row * FFD + gs * 8, W2b[0] + p * 2048 + tid * 8);
    }
  }
  __syncthreads();

  f32x4 acc2[8][2] = {};
  char* Hw = (char*)&H1s[wv][0];

  for (int c = 0; c < 32; ++c) {
    int cur = c & 1;
    if (c < 31) {
      const u16* w1n = w1 + (u64)(c + 1) * 64 * 128;
      const u16* w2n = w2 + (u64)(c + 1) * 64;
      u16* d1 = W1b[cur ^ 1];
      u16* d2 = W2b[cur ^ 1];
#pragma unroll
      for (int p = 0; p < 4; ++p) {
        int row = p * 16 + (tid >> 4);
        int gs = (tid & 15) ^ (row & 7);
        gload16(w1n + (u64)row * 128 + gs * 8, d1 + p * 2048 + tid * 8);
      }
#pragma unroll
      for (int p = 0; p < 4; ++p) {
        int row = p * 32 + (tid >> 3);
        int gs = (tid & 7) ^ (row & 7);
        gload16(w2n + (u64)row * FFD + gs * 8, d2 + p * 2048 + tid * 8);
      }
    }
    const u16* W1c = W1b[cur];
    const u16* W2c = W2b[cur];

    // ---- gemm1 ----
    f32x4 a1[4][2] = {};
#pragma unroll
    for (int ks = 0; ks < 4; ++ks) {
      bf16x8 af[4];
#pragma unroll
      for (int i = 0; i < 4; ++i) {
        int row = i * 16 + l15;
        int gz = (ks * 4 + g) ^ (row & 7);
        af[i] = ld_bf8(W1c + row * 128 + gz * 8);
      }
#pragma unroll
      for (int i = 0; i < 4; ++i)
#pragma unroll
        for (int j = 0; j < 2; ++j) a1[i][j] = mfma16(af[i], az[j][ks], a1[i][j]);
    }
    // ---- bias + relu -> wave-private H1 (swizzled) ----
#pragma unroll
    for (int i = 0; i < 4; ++i) {
      f32x4 bq = *(const f32x4*)(b1 + c * 64 + i * 16 + g * 4);
#pragma unroll
      for (int j = 0; j < 2; ++j) {
        int q = j * 16 + l15;
        float t0 = a1[i][j][0] + bq[0]; t0 = t0 > 0.f ? t0 : 0.f;
        float t1 = a1[i][j][1] + bq[1]; t1 = t1 > 0.f ? t1 : 0.f;
        float t2 = a1[i][j][2] + bq[2]; t2 = t2 > 0.f ? t2 : 0.f;
        float t3 = a1[i][j][3] + bq[3]; t3 = t3 > 0.f ? t3 : 0.f;
        int off = (q * 128 + i * 32 + g * 8) ^ ((q & 7) << 4);
        *(u64*)(Hw + off) = pack4bf(t0, t1, t2, t3);
      }
    }
    // ---- gemm2 ----
#pragma unroll
    for (int ks = 0; ks < 2; ++ks) {
      bf16x8 pb[2];
#pragma unroll
      for (int j = 0; j < 2; ++j) {
        int q = j * 16 + l15;
        int off = (q * 128 + ks * 64 + g * 16) ^ ((q & 7) << 4);
        pb[j] = ld_bf8((const u16*)(Hw + off));
      }
#pragma unroll
      for (int i = 0; i < 8; ++i) {
        int row = i * 16 + l15;
        int gz = (ks * 4 + g) ^ (row & 7);
        bf16x8 wf = ld_bf8(W2c + row * 64 + gz * 8);
#pragma unroll
        for (int j = 0; j < 2; ++j) acc2[i][j] = mfma16(wf, pb[j], acc2[i][j]);
      }
    }
    __syncthreads(); // drains vmcnt(0): stage(c+1) landed; buf[cur] reads done
  }

  // ---- epilogue: bias + residual + LN2, all in registers ----
  float s[2] = {0.f, 0.f}, s2[2] = {0.f, 0.f};
#pragma unroll
  for (int i = 0; i < 8; ++i) {
    f32x4 bq = *(const f32x4*)(b2 + i * 16 + g * 4);
#pragma unroll
    for (int j = 0; j < 2; ++j) {
      int q = qb + j * 16 + l15;
      u64 zo = *(const u64*)(zb + (u64)q * 128 + i * 16 + g * 4);
#pragma unroll
      for (int r = 0; r < 4; ++r) {
        float val = acc2[i][j][r] + bq[r] + bf2f((u16)(zo >> (16 * r)));
        acc2[i][j][r] = val;
        s[j] += val; s2[j] += val * val;
      }
    }
  }
  float mval[2], rstd[2];
#pragma unroll
  for (int j = 0; j < 2; ++j) {
    float a = s[j], b = s2[j];
    a += __shfl_xor(a, 16); a += __shfl_xor(a, 32);
    b += __shfl_xor(b, 16); b += __shfl_xor(b, 32);
    float mean = a * (1.0f / 128.0f);
    float var = b * (1.0f / 128.0f) - mean * mean;
    mval[j] = mean;
    rstd[j] = rsqrtf(var + LN_EPS);
  }
#pragma unroll
  for (int i = 0; i < 8; ++i) {
    f32x4 ls = *(const f32x4*)(lns + i * 16 + g * 4);
    f32x4 lb = *(const f32x4*)(lnb + i * 16 + g * 4);
#pragma unroll
    for (int j = 0; j < 2; ++j) {
      int q = qb + j * 16 + l15;
      u64 pk = pack4bf((acc2[i][j][0] - mval[j]) * rstd[j] * ls[0] + lb[0],
                       (acc2[i][j][1] - mval[j]) * rstd[j] * ls[1] + lb[1],
                       (acc2[i][j][2] - mval[j]) * rstd[j] * ls[2] + lb[2],
                       (acc2[i][j][3] - mval[j]) * rstd[j] * ls[3] + lb[3]);
      *(u64*)(zb + (u64)q * 128 + i * 16 + g * 4) = pk;
    }
  }
}

// ---------------- mean over seq ----------------
__global__ __launch_bounds__(256) void k_mean(const u16* zb, float* h) {
  __shared__ float part[4][128];
  int tid = threadIdx.x, bb = blockIdx.x;
  int d2 = tid & 63, lg = tid >> 6;
  float s0 = 0.f, s1 = 0.f;
  for (int li = 0; li < 64; ++li) {
    int l = lg * 64 + li;
    u32 v = *(const u32*)(zb + (u64)(bb * 256 + l) * 128 + d2 * 2);
    s0 += bf2f((u16)(v & 0xffffu));
    s1 += bf2f((u16)(v >> 16));
  }
  part[lg][d2 * 2] = s0;
  part[lg][d2 * 2 + 1] = s1;
  __syncthreads();
  if (tid < 128) {
    float s = part[0][tid] + part[1][tid] + part[2][tid] + part[3][tid];
    h[bb * 128 + tid] = s * (1.0f / 256.0f);
  }
}

// ---------------- head: tanh(tanh(h W1^T + b1) W2^T + b2) ----------------
__global__ __launch_bounds__(128) void k_head(const float* h, const float* w1, const float* b1,
                                              const float* w2, const float* b2, float* h2) {
  __shared__ float r0[128], r1[128];
  int tid = threadIdx.x, bb = blockIdx.x;
  r0[tid] = h[bb * 128 + tid];
  __syncthreads();
  float s = b1[tid];
  const float* wr = w1 + tid * 128;
  for (int k = 0; k < 128; ++k) s += r0[k] * wr[k];
  r1[tid] = tanhf(s);
  __syncthreads();
  float s2 = b2[tid];
  const float* wr2 = w2 + tid * 128;
  for (int k = 0; k < 128; ++k) s2 += r1[k] * wr2[k];
  h2[bb * 128 + tid] = tanhf(s2);
}

// ---------------- finalize ----------------
__global__ __launch_bounds__(128) void k_finalize(const float* h2, const float* w3, const float* b3,
                                                  float* nrm, float* out) {
  __shared__ float row[128];
  __shared__ float red[2];
  __shared__ float lg[3];
  int tid = threadIdx.x, i = blockIdx.x;
  float v = h2[i * 128 + tid];
  row[tid] = v;
  float sq = v * v;
#pragma unroll
  for (int o = 32; o; o >>= 1) sq += __shfl_xor(sq, o);
  if ((tid & 63) == 0) red[tid >> 6] = sq;
  __syncthreads();
  float rinv = rsqrtf(red[0] + red[1]);
  float nv = v * rinv;
  nrm[i * 128 + tid] = nv;
  int br = i >> 8, loc = i & 255;
  if (br == 0)      out[loc * 128 + tid] = nv;
  else if (br == 1) out[32768 + loc * 128 + tid] = v;
  else              out[65536 + loc * 128 + tid] = v;
  if (br == 0) {
    if (tid < 3) {
      float s = b3[tid];
      const float* wr = w3 + tid * 128;
      for (int k = 0; k < 128; ++k) s += row[k] * wr[k];
      lg[tid] = s;
    }
    __syncthreads();
    if (tid == 0) {
      float m = fmaxf(lg[0], fmaxf(lg[1], lg[2]));
      float e0 = __expf(lg[0] - m), e1 = __expf(lg[1] - m), e2 = __expf(lg[2] - m);
      float si = 1.0f / (e0 + e1 + e2);
      out[98304 + loc * 3 + 0] = e0 * si;
      out[98304 + loc * 3 + 1] = e1 * si;
      out[98304 + loc * 3 + 2] = e2 * si;
    }
  }
}

// ---------------- InfoNCE per-row partial ----------------
__global__ __launch_bounds__(256) void k_infonce(const float* nrm, float* partial) {
  __shared__ float nbi[128];
  __shared__ float red[8];
  __shared__ float posv;
  int tid = threadIdx.x, i = blockIdx.x;
  if (tid < 128) nbi[tid] = nrm[i * 128 + tid];
  __syncthreads();
  const float* a = nrm + (u64)(256 + tid) * 128;
  const float* b = nrm + (u64)(512 + tid) * 128;
  float s1 = 0.f, s2 = 0.f;
  for (int k = 0; k < 128; ++k) { s1 += nbi[k] * a[k]; s2 += nbi[k] * b[k]; }
  s1 *= 20.0f; s2 *= 20.0f;
  if (tid == i) posv = s1;
  float m = fmaxf(s1, s2);
#pragma unroll
  for (int o = 32; o; o >>= 1) m = fmaxf(m, __shfl_xor(m, o));
  if ((tid & 63) == 0) red[tid >> 6] = m;
  __syncthreads();
  float M = fmaxf(fmaxf(red[0], red[1]), fmaxf(red[2], red[3]));
  float e = __expf(s1 - M) + __expf(s2 - M);
#pragma unroll
  for (int o = 32; o; o >>= 1) e += __shfl_xor(e, o);
  if ((tid & 63) == 0) red[4 + (tid >> 6)] = e;
  __syncthreads();
  if (tid == 0) {
    float S = red[4] + red[5] + red[6] + red[7];
    partial[i] = logf(S) + M - posv;
  }
}

__global__ __launch_bounds__(256) void k_loss(const float* partial, float* out) {
  int tid = threadIdx.x;
  float v = partial[tid];
#pragma unroll
  for (int o = 32; o; o >>= 1) v += __shfl_xor(v, o);
  __shared__ float red[4];
  if ((tid & 63) == 0) red[tid >> 6] = v;
  __syncthreads();
  if (tid == 0) out[99072] = (red[0] + red[1] + red[2] + red[3]) * (1.0f / 256.0f);
}

extern "C" void kernel_launch(void* const* d_in, const int* in_sizes, int n_in,
                              void* d_out, int out_size, void* d_ws, size_t ws_size,
                              hipStream_t stream) {
  const float* x   = (const float*)d_in[0];
  const float* xp  = (const float*)d_in[1];
  const float* xn  = (const float*)d_in[2];
  const unsigned char* mk0 = (const unsigned char*)d_in[3];
  const unsigned char* mk1 = (const unsigned char*)d_in[4];
  const unsigned char* mk2 = (const unsigned char*)d_in[5];
  const float* w0   = (const float*)d_in[6];
  const float* b0   = (const float*)d_in[7];
  const float* wqkv = (const float*)d_in[8];
  const float* bqkv = (const float*)d_in[9];
  const float* wo   = (const float*)d_in[10];
  const float* bo   = (const float*)d_in[11];
  const float* wf1  = (const float*)d_in[12];
  const float* bf1  = (const float*)d_in[13];
  const float* wf2  = (const float*)d_in[14];
  const float* bf2v = (const float*)d_in[15];
  const float* l1s  = (const float*)d_in[16];
  const float* l1b  = (const float*)d_in[17];
  const float* l2s  = (const float*)d_in[18];
  const float* l2b  = (const float*)d_in[19];
  const float* w1   = (const float*)d_in[20];
  const float* b1   = (const float*)d_in[21];
  const float* w2   = (const float*)d_in[22];
  const float* b2   = (const float*)d_in[23];
  const float* w3   = (const float*)d_in[24];
  const float* b3   = (const float*)d_in[25];
  float* out = (float*)d_out;

  char* ws = (char*)d_ws;
  u16* zb    = (u16*)ws; ws += (size_t)MTOT * 128 * 2;
  u16* qkv   = (u16*)ws; ws += (size_t)MTOT * 384 * 2;
  u16* attno = (u16*)ws; ws += (size_t)MTOT * 128 * 2;
  u16* wqb   = (u16*)ws; ws += (size_t)3 * 384 * 128 * 2;
  u16* wob   = (u16*)ws; ws += (size_t)3 * 128 * 128 * 2;
  u16* wf1b  = (u16*)ws; ws += (size_t)3 * 2048 * 128 * 2;
  u16* wf2b  = (u16*)ws; ws += (size_t)3 * 128 * 2048 * 2;
  float* hbuf = (float*)ws; ws += (size_t)768 * 128 * 4;
  float* h2   = (float*)ws; ws += (size_t)768 * 128 * 4;
  float* nrm  = (float*)ws; ws += (size_t)768 * 128 * 4;
  float* partial = (float*)ws;

  k_cvt<<<72, 256, 0, stream>>>(wqkv, wqb, 3 * 384 * 128 / 8);
  k_cvt<<<24, 256, 0, stream>>>(wo, wob, 3 * 128 * 128 / 8);
  k_cvt<<<384, 256, 0, stream>>>(wf1, wf1b, 3 * 2048 * 128 / 8);
  k_cvt<<<384, 256, 0, stream>>>(wf2, wf2b, 3 * 128 * 2048 / 8);
  k_embed<<<12288, 256, 0, stream>>>(x, xp, xn, w0, b0, zb);

  for (int l = 0; l < 3; ++l) {
    k_qkv<<<dim3(1536, 3), 256, 0, stream>>>(zb, wqb + (size_t)l * 384 * 128,
                                             bqkv + l * 384, qkv);
    k_attn<<<3072, 256, 0, stream>>>(qkv, mk0, mk1, mk2, attno);
    k_oln<<<1536, 256, 0, stream>>>(attno, wob + (size_t)l * 128 * 128, bo + l * 128,
                                    l1s + l * 128, l1b + l * 128, zb);
    k_ffn<<<1536, 256, 0, stream>>>(zb, wf1b + (size_t)l * 2048 * 128, bf1 + l * 2048,
                                    wf2b + (size_t)l * 128 * 2048, bf2v + l * 128,
                                    l2s + l * 128, l2b + l * 128);
  }
  k_mean<<<768, 256, 0, stream>>>(zb, hbuf);
  k_head<<<768, 128, 0, stream>>>(hbuf, w1, b1, w2, b2, h2);
  k_finalize<<<768, 128, 0, stream>>>(h2, w3, b3, nrm, out);
  k_infonce<<<256, 256, 0, stream>>>(nrm, partial);
  k_loss<<<1, 256, 0, stream>>>(partial, out);
}